// Round 14
// baseline (209.300 us; speedup 1.0000x reference)
//
#include <hip/hip_runtime.h>
#include <hip/hip_bf16.h>

// ---------------- types & helpers ----------------
typedef __attribute__((ext_vector_type(8))) short short8;
typedef __attribute__((ext_vector_type(4))) short s16x4;
typedef __attribute__((ext_vector_type(4))) float f32x4;
typedef __attribute__((ext_vector_type(2))) unsigned int u32x2;

#define NWIN 256      // number of windows
#define NW   256      // tokens per window
#define CH   256      // channels
#define NH   8
#define DH   32
#define QKV_LD 768
#define ATTN_SCALE 0.17677669529663687f
#define LOG2E 1.4426950408889634f
#define QSCALE (ATTN_SCALE * LOG2E)   // folded into Q weights at prep

__device__ __forceinline__ unsigned short f2bf(float f) {
  union { float f; unsigned u; } v; v.f = f;
  unsigned r = v.u + 0x7FFFu + ((v.u >> 16) & 1u);   // round-to-nearest-even
  return (unsigned short)(r >> 16);
}
__device__ __forceinline__ float bf2f(unsigned short h) {
  union { unsigned u; float f; } v; v.u = ((unsigned)h) << 16;
  return v.f;
}
// XOR swizzle: 128-byte rows (8 x 16B slots) -- T2 pattern
__device__ __forceinline__ int swz128(int row, int kb) { return row * 128 + (kb ^ ((row & 7) << 4)); }
// async global->LDS, 16B per lane (dest must be linear: base + lane*16)
__device__ __forceinline__ void gload16(const unsigned short* g, unsigned short* l) {
  __builtin_amdgcn_global_load_lds((const __attribute__((address_space(1))) unsigned int*)(g),
                                   (__attribute__((address_space(3))) unsigned int*)(l), 16, 0, 0);
}

// ---------------- weight prep: transpose + hi/lo bf16 split; Q cols pre-scaled ----------------
__global__ __launch_bounds__(256) void k_prepw(const float* __restrict__ wqkv,
                                               const float* __restrict__ wout,
                                               unsigned short* __restrict__ wqh,
                                               unsigned short* __restrict__ wql,
                                               unsigned short* __restrict__ woh,
                                               unsigned short* __restrict__ wol) {
  int idx = blockIdx.x * 256 + threadIdx.x;       // 0..196607
  {
    int k = idx / 768, n = idx % 768;
    float v = wqkv[idx];
    if (n < 256) v *= QSCALE;                     // fold scale*log2e into Q
    unsigned short hi = f2bf(v);
    wqh[n * 256 + k] = hi;
    wql[n * 256 + k] = f2bf(v - bf2f(hi));
  }
  if (idx < 65536) {
    int k = idx >> 8, n = idx & 255;
    float v = wout[idx];
    unsigned short hi = f2bf(v);
    woh[n * 256 + k] = hi;
    wol[n * 256 + k] = f2bf(v - bf2f(hi));
  }
}

// ---------------- bias prep: bias2[h][q][k] = table[rel[q][k]][h] * log2(e) ----------------
__global__ __launch_bounds__(256) void k_prepbias(const float* __restrict__ table,
                                                  const int* __restrict__ relidx,
                                                  float* __restrict__ bias2) {
  int idx = blockIdx.x * 256 + threadIdx.x;       // 0..524287
  int h = idx >> 16;
  int qk = idx & 65535;
  bias2[idx] = table[relidx[qk] * 8 + h] * LOG2E;
}

// ---------------- LN + window gather (float4 loads) ----------------
__global__ __launch_bounds__(256) void k_ln(const float* __restrict__ x,
                                            const float* __restrict__ gamma,
                                            const float* __restrict__ beta,
                                            unsigned short* __restrict__ xn) {
  __shared__ unsigned short buf[256][66];
  __shared__ float stats[2][16][64];
  int bid = blockIdx.x;
  int d = bid >> 6, h = bid & 63;
  int t = threadIdx.x;
  int wq = (t & 15) << 2;      // w base: 0..60 step 4
  int cp = t >> 4;             // 0..15
  const float* xrow = x + (size_t)d * 4096 + (size_t)h * 64;
  float s0[4] = {0.f, 0.f, 0.f, 0.f}, s1[4] = {0.f, 0.f, 0.f, 0.f};
  for (int ci = 0; ci < 16; ++ci) {
    int c = ci * 16 + cp;
    f32x4 v = *(const f32x4*)(xrow + (size_t)c * 65536 + wq);
    unsigned pk01 = (unsigned)f2bf(v[0]) | ((unsigned)f2bf(v[1]) << 16);
    unsigned pk23 = (unsigned)f2bf(v[2]) | ((unsigned)f2bf(v[3]) << 16);
    *(unsigned*)&buf[c][wq]     = pk01;
    *(unsigned*)&buf[c][wq + 2] = pk23;
#pragma unroll
    for (int j = 0; j < 4; ++j) { s0[j] += v[j]; s1[j] += v[j] * v[j]; }
  }
#pragma unroll
  for (int j = 0; j < 4; ++j) { stats[0][cp][wq + j] = s0[j]; stats[1][cp][wq + j] = s1[j]; }
  __syncthreads();
  int lane = t & 63, wv = t >> 6;
  int winb = (d >> 2) * 64 + (h >> 3) * 8;
  int tokb = (d & 3) * 64 + (h & 7) * 8;
  for (int wi = 0; wi < 16; ++wi) {
    int w2 = wi * 4 + wv;
    float sum = 0.f, sq = 0.f;
#pragma unroll
    for (int i = 0; i < 16; ++i) { sum += stats[0][i][w2]; sq += stats[1][i][w2]; }
    float mu = sum * 0.00390625f;
    float var = sq * 0.00390625f - mu * mu;
    float rstd = rsqrtf(var + 1e-5f);
    int win = winb + (w2 >> 3);
    int tok = tokb + (w2 & 7);
    unsigned short* dst = xn + ((size_t)win * NW + tok) * CH;
    for (int cc = 0; cc < 4; ++cc) {
      int c = cc * 64 + lane;
      float v = bf2f(buf[c][w2]);
      dst[c] = f2bf((v - mu) * rstd * gamma[c] + beta[c]);
    }
  }
}

// ---------------- QKV GEMM (fully single-bf16 weights, head-major output) ----------------
// qkvH[(mat*8+head)][gtok][dh]: flat = ((mat*8+head)*65536 + gtok)*32 + dh
__global__ __launch_bounds__(256) void k_qkv(const unsigned short* __restrict__ xn,
                                             const unsigned short* __restrict__ bhi,
                                             unsigned short* __restrict__ qkvH) {
  __shared__ unsigned short sA[8192], sBh[8192];
  int t = threadIdx.x;
  int mbase = blockIdx.x << 7, nbase = blockIdx.y << 7;
  int wid = t >> 6, lane = t & 63;
  int wm = wid >> 1, wn = wid & 1;
  f32x4 acc[4][4];
#pragma unroll
  for (int i = 0; i < 4; ++i)
#pragma unroll
    for (int j = 0; j < 4; ++j) acc[i][j] = (f32x4)(0.f);
  for (int kt = 0; kt < 4; ++kt) {
#pragma unroll
    for (int i = 0; i < 4; ++i) {
      int ch = t + (i << 8);
      int row = ch >> 3, s = ch & 7;
      int gs = s ^ (row & 7);              // pre-swizzled source slot
      size_t go = (size_t)(mbase + row) * 256 + (kt << 6) + (gs << 3);
      size_t gb = (size_t)(nbase + row) * 256 + (kt << 6) + (gs << 3);
      gload16(xn + go,  sA  + ch * 8);     // linear LDS dest: byte ch*16
      gload16(bhi + gb, sBh + ch * 8);
    }
    __syncthreads();
#pragma unroll
    for (int kk = 0; kk < 2; ++kk) {
      int kb = (kk << 6) + ((lane >> 4) << 4);
      short8 a[4], bh[4];
#pragma unroll
      for (int mi = 0; mi < 4; ++mi) {
        int row = (wm << 6) + (mi << 4) + (lane & 15);
        a[mi] = *(const short8*)((char*)sA + swz128(row, kb));
      }
#pragma unroll
      for (int ni = 0; ni < 4; ++ni) {
        int row = (wn << 6) + (ni << 4) + (lane & 15);
        bh[ni] = *(const short8*)((char*)sBh + swz128(row, kb));
      }
#pragma unroll
      for (int mi = 0; mi < 4; ++mi)
#pragma unroll
        for (int ni = 0; ni < 4; ++ni)
          acc[mi][ni] = __builtin_amdgcn_mfma_f32_16x16x32_bf16(a[mi], bh[ni], acc[mi][ni], 0, 0, 0);
    }
    __syncthreads();
  }
#pragma unroll
  for (int mi = 0; mi < 4; ++mi)
#pragma unroll
    for (int ni = 0; ni < 4; ++ni)
#pragma unroll
      for (int r = 0; r < 4; ++r) {
        int m = mbase + (wm << 6) + (mi << 4) + ((lane >> 4) << 2) + r;
        int n = nbase + (wn << 6) + (ni << 4) + (lane & 15);
        int mat = n >> 8, hd = (n >> 5) & 7, dh = n & 31;
        qkvH[((size_t)(mat * 8 + hd) * 65536 + m) * 32 + dh] = f2bf(acc[mi][ni][r]);
      }
}

// ---------------- attention v14: denominator via ones-column MFMA (VALU -> matrix pipe) ----------------
// ol[qt] = sum_tok P[q][tok] computed by mfma(wP, ones); D rows (4g+r) match the
// output-write rows exactly, so the epilogue needs no shuffles at all.
__global__ __launch_bounds__(256) void k_attn(const unsigned short* __restrict__ qkvH,
                                              const float* __restrict__ bias2,
                                              unsigned short* __restrict__ attnout) {
  __shared__ unsigned short Vt[8192];    // [32 dh][256 tok] 512B rows, XOR swizzled (16KB)
  __shared__ unsigned short Kt[8192];    // [256 tok][32 dh] 64B rows, XOR swizzled (16KB)
  int win = blockIdx.x, head = blockIdx.y;
  int t = threadIdx.x, wid = t >> 6, lane = t & 63;
  int l15 = lane & 15, g = lane >> 4;
  const unsigned short* Qg = qkvH + ((size_t)(head)      * 65536 + win * 256) * 32;
  const unsigned short* Kg = qkvH + ((size_t)(8 + head)  * 65536 + win * 256) * 32;
  const unsigned short* Vg = qkvH + ((size_t)(16 + head) * 65536 + win * 256) * 32;

  { // stage V transposed: thread t handles V row tok=t (contiguous 64B rows -> coalesced)
    const unsigned short* vrow = Vg + (size_t)t * 32;
    short8 v0 = *(const short8*)(vrow);
    short8 v1 = *(const short8*)(vrow + 8);
    short8 v2 = *(const short8*)(vrow + 16);
    short8 v3 = *(const short8*)(vrow + 24);
    int tb = t * 2;
#pragma unroll
    for (int j = 0; j < 8; ++j) {
      int sj = tb ^ (j << 4);
      *(unsigned short*)((char*)Vt + (j)      * 512 + sj)       = (unsigned short)v0[j];
      *(unsigned short*)((char*)Vt + (8 + j)  * 512 + (sj ^ 8)) = (unsigned short)v1[j];
      *(unsigned short*)((char*)Vt + (16 + j) * 512 + sj)       = (unsigned short)v2[j];
      *(unsigned short*)((char*)Vt + (24 + j) * 512 + (sj ^ 8)) = (unsigned short)v3[j];
    }
  }
  { // stage K packed: thread t -> row t (contiguous source), chunk-XOR swizzle
    const unsigned short* krow = Kg + (size_t)t * 32;
    short8 k0 = *(const short8*)(krow);
    short8 k1 = *(const short8*)(krow + 8);
    short8 k2 = *(const short8*)(krow + 16);
    short8 k3 = *(const short8*)(krow + 24);
    char* kd = (char*)Kt + t * 64;
    int ks = ((t >> 1) & 3) << 4;
    *(short8*)(kd + (0  ^ ks)) = k0;
    *(short8*)(kd + (16 ^ ks)) = k1;
    *(short8*)(kd + (32 ^ ks)) = k2;
    *(short8*)(kd + (48 ^ ks)) = k3;
  }
  short8 bq[4];
#pragma unroll
  for (int qt = 0; qt < 4; ++qt)
    bq[qt] = *(const short8*)(Qg + (size_t)(wid * 64 + qt * 16 + l15) * 32 + g * 8);

  f32x4 o[4][2];
  f32x4 ol[4];   // denominator accumulators (rows 4g+r, same as output rows)
#pragma unroll
  for (int qt = 0; qt < 4; ++qt) {
    o[qt][0] = (f32x4)(0.f); o[qt][1] = (f32x4)(0.f); ol[qt] = (f32x4)(0.f);
  }
  s16x4 onesb;   // bf16 1.0 in all 4 k-slots
  onesb[0] = onesb[1] = onesb[2] = onesb[3] = (short)0x3F80;
  const f32x4 zero = (f32x4)(0.f);
  const float* bthread = bias2 + ((size_t)head << 16) + (size_t)(wid * 64 + l15) * 256 + g * 4;
  int vswz = ((l15 & 7) << 4) ^ (l15 & 8);   // V read swizzle
  int kswz = ((l15 >> 1) & 3) << 4;          // K read swizzle (lane-constant)

  // prefetch bias for (ck=0, qt=0)
  f32x4 nb0, nb1, nb2, nb3;
  {
    const float* bp = bthread;
    nb0 = *(const f32x4*)(bp);
    nb1 = *(const f32x4*)(bp + 16);
    nb2 = *(const f32x4*)(bp + 32);
    nb3 = *(const f32x4*)(bp + 48);
  }

  __syncthreads();

  for (int ck = 0; ck < 4; ++ck) {
    short8 ak[4];
#pragma unroll
    for (int tt = 0; tt < 4; ++tt)
      ak[tt] = *(const short8*)((char*)Kt + (ck * 64 + tt * 16 + l15) * 64 + ((g * 16) ^ kswz));
#pragma unroll
    for (int qt = 0; qt < 4; ++qt) {
      // consume current bias, then immediately issue next iteration's loads
      f32x4 cb[4];
      cb[0] = nb0; cb[1] = nb1; cb[2] = nb2; cb[3] = nb3;
      if (!(ck == 3 && qt == 3)) {
        int nqt = (qt + 1) & 3;
        int nck = (qt == 3) ? ck + 1 : ck;
        const float* bp = bthread + (size_t)nqt * 4096 + nck * 64;  // floats
        nb0 = *(const f32x4*)(bp);
        nb1 = *(const f32x4*)(bp + 16);
        nb2 = *(const f32x4*)(bp + 32);
        nb3 = *(const f32x4*)(bp + 48);
      }
      f32x4 z[4];
      __builtin_amdgcn_s_setprio(1);
#pragma unroll
      for (int tt = 0; tt < 4; ++tt)
        z[tt] = __builtin_amdgcn_mfma_f32_16x16x32_bf16(ak[tt], bq[qt], zero, 0, 0, 0);
      __builtin_amdgcn_s_setprio(0);
      u32x2 wPq[4];
#pragma unroll
      for (int tt = 0; tt < 4; ++tt) {
        float p0 = __builtin_amdgcn_exp2f(z[tt][0] + cb[tt][0]);
        float p1 = __builtin_amdgcn_exp2f(z[tt][1] + cb[tt][1]);
        float p2 = __builtin_amdgcn_exp2f(z[tt][2] + cb[tt][2]);
        float p3 = __builtin_amdgcn_exp2f(z[tt][3] + cb[tt][3]);
        __hip_bfloat162 lo = __float22bfloat162_rn(float2{p0, p1});
        __hip_bfloat162 hi = __float22bfloat162_rn(float2{p2, p3});
        u32x2 pk;
        pk.x = *(unsigned int*)&lo;
        pk.y = *(unsigned int*)&hi;
        wPq[tt] = pk;
      }
      // PV for this qt (K=16 per tt), P straight from registers.
      // ol picks up the denominator on the matrix pipe (B = ones).
      __builtin_amdgcn_s_setprio(1);
#pragma unroll
      for (int tt = 0; tt < 4; ++tt) {
        int tokb = (ck * 128 + tt * 32 + g * 8) ^ vswz;
        s16x4 pa = __builtin_bit_cast(s16x4, wPq[tt]);
        ol[qt] = __builtin_amdgcn_mfma_f32_16x16x16bf16_1k(pa, onesb, ol[qt], 0, 0, 0);
#pragma unroll
        for (int dht = 0; dht < 2; ++dht) {
          s16x4 vb = *(const s16x4*)((char*)Vt + (dht * 16 + l15) * 512 + tokb);
          o[qt][dht] = __builtin_amdgcn_mfma_f32_16x16x16bf16_1k(pa, vb, o[qt][dht], 0, 0, 0);
        }
      }
      __builtin_amdgcn_s_setprio(0);
    }
  }
  // epilogue: rows of ol match output rows (4g+r) -> no shuffles needed
#pragma unroll
  for (int qt = 0; qt < 4; ++qt) {
#pragma unroll
    for (int r = 0; r < 4; ++r) {
      float lr = 1.0f / ol[qt][r];
      int q = wid * 64 + qt * 16 + g * 4 + r;
      unsigned short* dst = attnout + ((size_t)(win * NW + q)) * CH + head * DH + l15;
      dst[0]  = f2bf(o[qt][0][r] * lr);
      dst[16] = f2bf(o[qt][1][r] * lr);
    }
  }
}

// ---------------- out-proj GEMM + bias + window-merge scatter ----------------
union SmemOP {
  struct { unsigned short A[8192], Bh[8192], Bl[8192]; } st;
  float ot[64][129];
};
__global__ __launch_bounds__(256) void k_outproj(const unsigned short* __restrict__ attnout,
                                                 const unsigned short* __restrict__ bhi,
                                                 const unsigned short* __restrict__ blo,
                                                 const float* __restrict__ bo,
                                                 float* __restrict__ out) {
  __shared__ SmemOP sm;
  int t = threadIdx.x;
  int mbase = blockIdx.x << 7, nbase = blockIdx.y << 7;
  int wid = t >> 6, lane = t & 63;
  int wm = wid >> 1, wn = wid & 1;
  f32x4 acc[4][4];
#pragma unroll
  for (int i = 0; i < 4; ++i)
#pragma unroll
    for (int j = 0; j < 4; ++j) acc[i][j] = (f32x4)(0.f);
  for (int kt = 0; kt < 4; ++kt) {
#pragma unroll
    for (int i = 0; i < 4; ++i) {
      int ch = t + (i << 8);
      int row = ch >> 3, c16 = ch & 7;
      size_t go = (size_t)(mbase + row) * 256 + (kt << 6) + (c16 << 3);
      short8 va = *(const short8*)(attnout + go);
      *(short8*)((char*)sm.st.A + swz128(row, c16 << 4)) = va;
      size_t gb = (size_t)(nbase + row) * 256 + (kt << 6) + (c16 << 3);
      short8 vh = *(const short8*)(bhi + gb);
      *(short8*)((char*)sm.st.Bh + swz128(row, c16 << 4)) = vh;
      short8 vl = *(const short8*)(blo + gb);
      *(short8*)((char*)sm.st.Bl + swz128(row, c16 << 4)) = vl;
    }
    __syncthreads();
#pragma unroll
    for (int kk = 0; kk < 2; ++kk) {
      int kb = (kk << 6) + ((lane >> 4) << 4);
      short8 a[4], bh[4], bl[4];
#pragma unroll
      for (int mi = 0; mi < 4; ++mi) {
        int row = (wm << 6) + (mi << 4) + (lane & 15);
        a[mi] = *(const short8*)((char*)sm.st.A + swz128(row, kb));
      }
#pragma unroll
      for (int ni = 0; ni < 4; ++ni) {
        int row = (wn << 6) + (ni << 4) + (lane & 15);
        bh[ni] = *(const short8*)((char*)sm.st.Bh + swz128(row, kb));
        bl[ni] = *(const short8*)((char*)sm.st.Bl + swz128(row, kb));
      }
#pragma unroll
      for (int mi = 0; mi < 4; ++mi)
#pragma unroll
        for (int ni = 0; ni < 4; ++ni) {
          acc[mi][ni] = __builtin_amdgcn_mfma_f32_16x16x32_bf16(a[mi], bh[ni], acc[mi][ni], 0, 0, 0);
          acc[mi][ni] = __builtin_amdgcn_mfma_f32_16x16x32_bf16(a[mi], bl[ni], acc[mi][ni], 0, 0, 0);
        }
    }
    __syncthreads();
  }
  int win = mbase >> 8;
  int tokbase = mbase & 255;
  int gd = win >> 6, gh = (win >> 3) & 7, gw = win & 7;
  size_t posw = (size_t)gd * 4 * 4096 + (size_t)gh * 8 * 64 + (size_t)gw * 8;
  for (int half = 0; half < 2; ++half) {
    if (wm == half) {
#pragma unroll
      for (int mi = 0; mi < 4; ++mi)
#pragma unroll
        for (int ni = 0; ni < 4; ++ni)
#pragma unroll
          for (int r = 0; r < 4; ++r)
            sm.ot[(mi << 4) + ((lane >> 4) << 2) + r][(wn << 6) + (ni << 4) + (lane & 15)] = acc[mi][ni][r];
    }
    __syncthreads();
    int tok = tokbase + half * 64 + lane;
    int td = tok >> 6, th = (tok >> 3) & 7, tw = tok & 7;
    size_t pos = posw + (size_t)td * 4096 + (size_t)th * 64 + tw;
    for (int cc = 0; cc < 32; ++cc) {
      int c = (cc << 2) + wid;
      float v = sm.ot[lane][c] + bo[nbase + c];
      out[(size_t)(nbase + c) * 65536 + pos] = v;
    }
    __syncthreads();
  }
}

// ---------------- launch ----------------
extern "C" void kernel_launch(void* const* d_in, const int* in_sizes, int n_in,
                              void* d_out, int out_size, void* d_ws, size_t ws_size,
                              hipStream_t stream) {
  const float* x     = (const float*)d_in[0];
  const float* gamma = (const float*)d_in[1];
  const float* beta  = (const float*)d_in[2];
  const float* wqkv  = (const float*)d_in[3];
  const float* wout  = (const float*)d_in[4];
  const float* bout  = (const float*)d_in[5];
  const float* btab  = (const float*)d_in[6];
  const int*   ridx  = (const int*)d_in[7];
  float* out = (float*)d_out;
  char* ws = (char*)d_ws;
  unsigned short* xn   = (unsigned short*)(ws);                  // 33,554,432 B
  unsigned short* qkv  = (unsigned short*)(ws + 33554432);       // 100,663,296 B (head-major)
  unsigned short* wqh  = (unsigned short*)(ws + 134217728);
  unsigned short* wql  = (unsigned short*)(ws + 134610944);
  unsigned short* woh  = (unsigned short*)(ws + 135004160);
  unsigned short* wol  = (unsigned short*)(ws + 135135232);
  float* bias2         = (float*)(ws + 135266304);
  unsigned short* attnout = xn;  // xn dead after k_qkv

  k_prepw<<<dim3(768), dim3(256), 0, stream>>>(wqkv, wout, wqh, wql, woh, wol);
  k_prepbias<<<dim3(2048), dim3(256), 0, stream>>>(btab, ridx, bias2);
  k_ln<<<dim3(1024), dim3(256), 0, stream>>>(x, gamma, beta, xn);
  k_qkv<<<dim3(512, 6), dim3(256), 0, stream>>>(xn, wqh, qkv);
  k_attn<<<dim3(256, 8), dim3(256), 0, stream>>>(qkv, bias2, attnout);
  k_outproj<<<dim3(512, 2), dim3(256), 0, stream>>>(attnout, woh, wol, bout, out);
}

// Round 15
// 207.575 us; speedup vs baseline: 1.0083x; 1.0083x over previous
//
#include <hip/hip_runtime.h>
#include <hip/hip_bf16.h>

// ---------------- types & helpers ----------------
typedef __attribute__((ext_vector_type(8))) short short8;
typedef __attribute__((ext_vector_type(4))) short s16x4;
typedef __attribute__((ext_vector_type(4))) float f32x4;
typedef __attribute__((ext_vector_type(2))) unsigned int u32x2;

#define NWIN 256      // number of windows
#define NW   256      // tokens per window
#define CH   256      // channels
#define NH   8
#define DH   32
#define QKV_LD 768
#define ATTN_SCALE 0.17677669529663687f
#define LOG2E 1.4426950408889634f
#define QSCALE (ATTN_SCALE * LOG2E)   // folded into Q weights at prep

__device__ __forceinline__ unsigned short f2bf(float f) {
  union { float f; unsigned u; } v; v.f = f;
  unsigned r = v.u + 0x7FFFu + ((v.u >> 16) & 1u);   // round-to-nearest-even
  return (unsigned short)(r >> 16);
}
__device__ __forceinline__ float bf2f(unsigned short h) {
  union { unsigned u; float f; } v; v.u = ((unsigned)h) << 16;
  return v.f;
}
// XOR swizzle: 128-byte rows (8 x 16B slots) -- T2 pattern
__device__ __forceinline__ int swz128(int row, int kb) { return row * 128 + (kb ^ ((row & 7) << 4)); }
// async global->LDS, 16B per lane (dest must be linear: base + lane*16)
__device__ __forceinline__ void gload16(const unsigned short* g, unsigned short* l) {
  __builtin_amdgcn_global_load_lds((const __attribute__((address_space(1))) unsigned int*)(g),
                                   (__attribute__((address_space(3))) unsigned int*)(l), 16, 0, 0);
}

// ---------------- weight prep: transpose + hi/lo bf16 split; Q cols pre-scaled ----------------
__global__ __launch_bounds__(256) void k_prepw(const float* __restrict__ wqkv,
                                               const float* __restrict__ wout,
                                               unsigned short* __restrict__ wqh,
                                               unsigned short* __restrict__ wql,
                                               unsigned short* __restrict__ woh,
                                               unsigned short* __restrict__ wol) {
  int idx = blockIdx.x * 256 + threadIdx.x;       // 0..196607
  {
    int k = idx / 768, n = idx % 768;
    float v = wqkv[idx];
    if (n < 256) v *= QSCALE;                     // fold scale*log2e into Q
    unsigned short hi = f2bf(v);
    wqh[n * 256 + k] = hi;
    wql[n * 256 + k] = f2bf(v - bf2f(hi));
  }
  if (idx < 65536) {
    int k = idx >> 8, n = idx & 255;
    float v = wout[idx];
    unsigned short hi = f2bf(v);
    woh[n * 256 + k] = hi;
    wol[n * 256 + k] = f2bf(v - bf2f(hi));
  }
}

// ---------------- bias prep: bias2[h][q][k] = table[rel[q][k]][h] * log2(e) ----------------
__global__ __launch_bounds__(256) void k_prepbias(const float* __restrict__ table,
                                                  const int* __restrict__ relidx,
                                                  float* __restrict__ bias2) {
  int idx = blockIdx.x * 256 + threadIdx.x;       // 0..524287
  int h = idx >> 16;
  int qk = idx & 65535;
  bias2[idx] = table[relidx[qk] * 8 + h] * LOG2E;
}

// ---------------- LN + window gather (float4 loads) ----------------
__global__ __launch_bounds__(256) void k_ln(const float* __restrict__ x,
                                            const float* __restrict__ gamma,
                                            const float* __restrict__ beta,
                                            unsigned short* __restrict__ xn) {
  __shared__ unsigned short buf[256][66];
  __shared__ float stats[2][16][64];
  int bid = blockIdx.x;
  int d = bid >> 6, h = bid & 63;
  int t = threadIdx.x;
  int wq = (t & 15) << 2;      // w base: 0..60 step 4
  int cp = t >> 4;             // 0..15
  const float* xrow = x + (size_t)d * 4096 + (size_t)h * 64;
  float s0[4] = {0.f, 0.f, 0.f, 0.f}, s1[4] = {0.f, 0.f, 0.f, 0.f};
  for (int ci = 0; ci < 16; ++ci) {
    int c = ci * 16 + cp;
    f32x4 v = *(const f32x4*)(xrow + (size_t)c * 65536 + wq);
    unsigned pk01 = (unsigned)f2bf(v[0]) | ((unsigned)f2bf(v[1]) << 16);
    unsigned pk23 = (unsigned)f2bf(v[2]) | ((unsigned)f2bf(v[3]) << 16);
    *(unsigned*)&buf[c][wq]     = pk01;
    *(unsigned*)&buf[c][wq + 2] = pk23;
#pragma unroll
    for (int j = 0; j < 4; ++j) { s0[j] += v[j]; s1[j] += v[j] * v[j]; }
  }
#pragma unroll
  for (int j = 0; j < 4; ++j) { stats[0][cp][wq + j] = s0[j]; stats[1][cp][wq + j] = s1[j]; }
  __syncthreads();
  int lane = t & 63, wv = t >> 6;
  int winb = (d >> 2) * 64 + (h >> 3) * 8;
  int tokb = (d & 3) * 64 + (h & 7) * 8;
  for (int wi = 0; wi < 16; ++wi) {
    int w2 = wi * 4 + wv;
    float sum = 0.f, sq = 0.f;
#pragma unroll
    for (int i = 0; i < 16; ++i) { sum += stats[0][i][w2]; sq += stats[1][i][w2]; }
    float mu = sum * 0.00390625f;
    float var = sq * 0.00390625f - mu * mu;
    float rstd = rsqrtf(var + 1e-5f);
    int win = winb + (w2 >> 3);
    int tok = tokb + (w2 & 7);
    unsigned short* dst = xn + ((size_t)win * NW + tok) * CH;
    for (int cc = 0; cc < 4; ++cc) {
      int c = cc * 64 + lane;
      float v = bf2f(buf[c][w2]);
      dst[c] = f2bf((v - mu) * rstd * gamma[c] + beta[c]);
    }
  }
}

// ---------------- QKV GEMM (fully single-bf16 weights, head-major output) ----------------
// qkvH[(mat*8+head)][gtok][dh]: flat = ((mat*8+head)*65536 + gtok)*32 + dh
__global__ __launch_bounds__(256) void k_qkv(const unsigned short* __restrict__ xn,
                                             const unsigned short* __restrict__ bhi,
                                             unsigned short* __restrict__ qkvH) {
  __shared__ unsigned short sA[8192], sBh[8192];
  int t = threadIdx.x;
  int mbase = blockIdx.x << 7, nbase = blockIdx.y << 7;
  int wid = t >> 6, lane = t & 63;
  int wm = wid >> 1, wn = wid & 1;
  f32x4 acc[4][4];
#pragma unroll
  for (int i = 0; i < 4; ++i)
#pragma unroll
    for (int j = 0; j < 4; ++j) acc[i][j] = (f32x4)(0.f);
  for (int kt = 0; kt < 4; ++kt) {
#pragma unroll
    for (int i = 0; i < 4; ++i) {
      int ch = t + (i << 8);
      int row = ch >> 3, s = ch & 7;
      int gs = s ^ (row & 7);              // pre-swizzled source slot
      size_t go = (size_t)(mbase + row) * 256 + (kt << 6) + (gs << 3);
      size_t gb = (size_t)(nbase + row) * 256 + (kt << 6) + (gs << 3);
      gload16(xn + go,  sA  + ch * 8);     // linear LDS dest: byte ch*16
      gload16(bhi + gb, sBh + ch * 8);
    }
    __syncthreads();
#pragma unroll
    for (int kk = 0; kk < 2; ++kk) {
      int kb = (kk << 6) + ((lane >> 4) << 4);
      short8 a[4], bh[4];
#pragma unroll
      for (int mi = 0; mi < 4; ++mi) {
        int row = (wm << 6) + (mi << 4) + (lane & 15);
        a[mi] = *(const short8*)((char*)sA + swz128(row, kb));
      }
#pragma unroll
      for (int ni = 0; ni < 4; ++ni) {
        int row = (wn << 6) + (ni << 4) + (lane & 15);
        bh[ni] = *(const short8*)((char*)sBh + swz128(row, kb));
      }
#pragma unroll
      for (int mi = 0; mi < 4; ++mi)
#pragma unroll
        for (int ni = 0; ni < 4; ++ni)
          acc[mi][ni] = __builtin_amdgcn_mfma_f32_16x16x32_bf16(a[mi], bh[ni], acc[mi][ni], 0, 0, 0);
    }
    __syncthreads();
  }
#pragma unroll
  for (int mi = 0; mi < 4; ++mi)
#pragma unroll
    for (int ni = 0; ni < 4; ++ni)
#pragma unroll
      for (int r = 0; r < 4; ++r) {
        int m = mbase + (wm << 6) + (mi << 4) + ((lane >> 4) << 2) + r;
        int n = nbase + (wn << 6) + (ni << 4) + (lane & 15);
        int mat = n >> 8, hd = (n >> 5) & 7, dh = n & 31;
        qkvH[((size_t)(mat * 8 + hd) * 65536 + m) * 32 + dh] = f2bf(acc[mi][ni][r]);
      }
}

// ---------------- attention v15: prefetched bias as MFMA C-operand (r10 fold + r11 prefetch) ----------------
// z = mfma(K, Q_prescaled, C=cb_prefetched) -> exp2 directly; no adds, no load stall.
// Denominator back to r13's VALU accumulation (r14's ones-MFMA cost occupancy).
__global__ __launch_bounds__(256) void k_attn(const unsigned short* __restrict__ qkvH,
                                              const float* __restrict__ bias2,
                                              unsigned short* __restrict__ attnout) {
  __shared__ unsigned short Vt[8192];    // [32 dh][256 tok] 512B rows, XOR swizzled (16KB)
  __shared__ unsigned short Kt[8192];    // [256 tok][32 dh] 64B rows, XOR swizzled (16KB)
  int win = blockIdx.x, head = blockIdx.y;
  int t = threadIdx.x, wid = t >> 6, lane = t & 63;
  int l15 = lane & 15, g = lane >> 4;
  const unsigned short* Qg = qkvH + ((size_t)(head)      * 65536 + win * 256) * 32;
  const unsigned short* Kg = qkvH + ((size_t)(8 + head)  * 65536 + win * 256) * 32;
  const unsigned short* Vg = qkvH + ((size_t)(16 + head) * 65536 + win * 256) * 32;

  { // stage V transposed: thread t handles V row tok=t (contiguous 64B rows -> coalesced)
    const unsigned short* vrow = Vg + (size_t)t * 32;
    short8 v0 = *(const short8*)(vrow);
    short8 v1 = *(const short8*)(vrow + 8);
    short8 v2 = *(const short8*)(vrow + 16);
    short8 v3 = *(const short8*)(vrow + 24);
    int tb = t * 2;
#pragma unroll
    for (int j = 0; j < 8; ++j) {
      int sj = tb ^ (j << 4);
      *(unsigned short*)((char*)Vt + (j)      * 512 + sj)       = (unsigned short)v0[j];
      *(unsigned short*)((char*)Vt + (8 + j)  * 512 + (sj ^ 8)) = (unsigned short)v1[j];
      *(unsigned short*)((char*)Vt + (16 + j) * 512 + sj)       = (unsigned short)v2[j];
      *(unsigned short*)((char*)Vt + (24 + j) * 512 + (sj ^ 8)) = (unsigned short)v3[j];
    }
  }
  { // stage K packed: thread t -> row t (contiguous source), chunk-XOR swizzle
    const unsigned short* krow = Kg + (size_t)t * 32;
    short8 k0 = *(const short8*)(krow);
    short8 k1 = *(const short8*)(krow + 8);
    short8 k2 = *(const short8*)(krow + 16);
    short8 k3 = *(const short8*)(krow + 24);
    char* kd = (char*)Kt + t * 64;
    int ks = ((t >> 1) & 3) << 4;
    *(short8*)(kd + (0  ^ ks)) = k0;
    *(short8*)(kd + (16 ^ ks)) = k1;
    *(short8*)(kd + (32 ^ ks)) = k2;
    *(short8*)(kd + (48 ^ ks)) = k3;
  }
  short8 bq[4];
#pragma unroll
  for (int qt = 0; qt < 4; ++qt)
    bq[qt] = *(const short8*)(Qg + (size_t)(wid * 64 + qt * 16 + l15) * 32 + g * 8);

  f32x4 o[4][2];
#pragma unroll
  for (int qt = 0; qt < 4; ++qt) { o[qt][0] = (f32x4)(0.f); o[qt][1] = (f32x4)(0.f); }
  float l_[4] = {0.f, 0.f, 0.f, 0.f};
  const float* bthread = bias2 + ((size_t)head << 16) + (size_t)(wid * 64 + l15) * 256 + g * 4;
  int vswz = ((l15 & 7) << 4) ^ (l15 & 8);   // V read swizzle
  int kswz = ((l15 >> 1) & 3) << 4;          // K read swizzle (lane-constant)

  // prefetch bias for (ck=0, qt=0)
  f32x4 nb0, nb1, nb2, nb3;
  {
    const float* bp = bthread;
    nb0 = *(const f32x4*)(bp);
    nb1 = *(const f32x4*)(bp + 16);
    nb2 = *(const f32x4*)(bp + 32);
    nb3 = *(const f32x4*)(bp + 48);
  }

  __syncthreads();

  for (int ck = 0; ck < 4; ++ck) {
    short8 ak[4];
#pragma unroll
    for (int tt = 0; tt < 4; ++tt)
      ak[tt] = *(const short8*)((char*)Kt + (ck * 64 + tt * 16 + l15) * 64 + ((g * 16) ^ kswz));
#pragma unroll
    for (int qt = 0; qt < 4; ++qt) {
      // consume current (prefetched) bias as MFMA C-operand; issue next prefetch now
      f32x4 cb[4];
      cb[0] = nb0; cb[1] = nb1; cb[2] = nb2; cb[3] = nb3;
      if (!(ck == 3 && qt == 3)) {
        int nqt = (qt + 1) & 3;
        int nck = (qt == 3) ? ck + 1 : ck;
        const float* bp = bthread + (size_t)nqt * 4096 + nck * 64;  // floats
        nb0 = *(const f32x4*)(bp);
        nb1 = *(const f32x4*)(bp + 16);
        nb2 = *(const f32x4*)(bp + 32);
        nb3 = *(const f32x4*)(bp + 48);
      }
      f32x4 z[4];
      __builtin_amdgcn_s_setprio(1);
#pragma unroll
      for (int tt = 0; tt < 4; ++tt)
        z[tt] = __builtin_amdgcn_mfma_f32_16x16x32_bf16(ak[tt], bq[qt], cb[tt], 0, 0, 0);
      __builtin_amdgcn_s_setprio(0);
      u32x2 wPq[4];
#pragma unroll
      for (int tt = 0; tt < 4; ++tt) {
        float p0 = __builtin_amdgcn_exp2f(z[tt][0]);
        float p1 = __builtin_amdgcn_exp2f(z[tt][1]);
        float p2 = __builtin_amdgcn_exp2f(z[tt][2]);
        float p3 = __builtin_amdgcn_exp2f(z[tt][3]);
        l_[qt] += (p0 + p1) + (p2 + p3);
        __hip_bfloat162 lo = __float22bfloat162_rn(float2{p0, p1});
        __hip_bfloat162 hi = __float22bfloat162_rn(float2{p2, p3});
        u32x2 pk;
        pk.x = *(unsigned int*)&lo;
        pk.y = *(unsigned int*)&hi;
        wPq[tt] = pk;
      }
      // PV for this qt (K=16 per tt), P straight from registers
      __builtin_amdgcn_s_setprio(1);
#pragma unroll
      for (int tt = 0; tt < 4; ++tt) {
        int tokb = (ck * 128 + tt * 32 + g * 8) ^ vswz;
        s16x4 pa = __builtin_bit_cast(s16x4, wPq[tt]);
#pragma unroll
        for (int dht = 0; dht < 2; ++dht) {
          s16x4 vb = *(const s16x4*)((char*)Vt + (dht * 16 + l15) * 512 + tokb);
          o[qt][dht] = __builtin_amdgcn_mfma_f32_16x16x16bf16_1k(pa, vb, o[qt][dht], 0, 0, 0);
        }
      }
      __builtin_amdgcn_s_setprio(0);
    }
  }
#pragma unroll
  for (int qt = 0; qt < 4; ++qt) {
    float lq = l_[qt];
    lq += __shfl_xor(lq, 16);
    lq += __shfl_xor(lq, 32);
    float linv = 1.0f / lq;
#pragma unroll
    for (int r = 0; r < 4; ++r) {
      float lr = __shfl(linv, g * 4 + r);
      int q = wid * 64 + qt * 16 + g * 4 + r;
      unsigned short* dst = attnout + ((size_t)(win * NW + q)) * CH + head * DH + l15;
      dst[0]  = f2bf(o[qt][0][r] * lr);
      dst[16] = f2bf(o[qt][1][r] * lr);
    }
  }
}

// ---------------- out-proj GEMM + bias + window-merge scatter ----------------
union SmemOP {
  struct { unsigned short A[8192], Bh[8192], Bl[8192]; } st;
  float ot[64][129];
};
__global__ __launch_bounds__(256) void k_outproj(const unsigned short* __restrict__ attnout,
                                                 const unsigned short* __restrict__ bhi,
                                                 const unsigned short* __restrict__ blo,
                                                 const float* __restrict__ bo,
                                                 float* __restrict__ out) {
  __shared__ SmemOP sm;
  int t = threadIdx.x;
  int mbase = blockIdx.x << 7, nbase = blockIdx.y << 7;
  int wid = t >> 6, lane = t & 63;
  int wm = wid >> 1, wn = wid & 1;
  f32x4 acc[4][4];
#pragma unroll
  for (int i = 0; i < 4; ++i)
#pragma unroll
    for (int j = 0; j < 4; ++j) acc[i][j] = (f32x4)(0.f);
  for (int kt = 0; kt < 4; ++kt) {
#pragma unroll
    for (int i = 0; i < 4; ++i) {
      int ch = t + (i << 8);
      int row = ch >> 3, c16 = ch & 7;
      size_t go = (size_t)(mbase + row) * 256 + (kt << 6) + (c16 << 3);
      short8 va = *(const short8*)(attnout + go);
      *(short8*)((char*)sm.st.A + swz128(row, c16 << 4)) = va;
      size_t gb = (size_t)(nbase + row) * 256 + (kt << 6) + (c16 << 3);
      short8 vh = *(const short8*)(bhi + gb);
      *(short8*)((char*)sm.st.Bh + swz128(row, c16 << 4)) = vh;
      short8 vl = *(const short8*)(blo + gb);
      *(short8*)((char*)sm.st.Bl + swz128(row, c16 << 4)) = vl;
    }
    __syncthreads();
#pragma unroll
    for (int kk = 0; kk < 2; ++kk) {
      int kb = (kk << 6) + ((lane >> 4) << 4);
      short8 a[4], bh[4], bl[4];
#pragma unroll
      for (int mi = 0; mi < 4; ++mi) {
        int row = (wm << 6) + (mi << 4) + (lane & 15);
        a[mi] = *(const short8*)((char*)sm.st.A + swz128(row, kb));
      }
#pragma unroll
      for (int ni = 0; ni < 4; ++ni) {
        int row = (wn << 6) + (ni << 4) + (lane & 15);
        bh[ni] = *(const short8*)((char*)sm.st.Bh + swz128(row, kb));
        bl[ni] = *(const short8*)((char*)sm.st.Bl + swz128(row, kb));
      }
#pragma unroll
      for (int mi = 0; mi < 4; ++mi)
#pragma unroll
        for (int ni = 0; ni < 4; ++ni) {
          acc[mi][ni] = __builtin_amdgcn_mfma_f32_16x16x32_bf16(a[mi], bh[ni], acc[mi][ni], 0, 0, 0);
          acc[mi][ni] = __builtin_amdgcn_mfma_f32_16x16x32_bf16(a[mi], bl[ni], acc[mi][ni], 0, 0, 0);
        }
    }
    __syncthreads();
  }
  int win = mbase >> 8;
  int tokbase = mbase & 255;
  int gd = win >> 6, gh = (win >> 3) & 7, gw = win & 7;
  size_t posw = (size_t)gd * 4 * 4096 + (size_t)gh * 8 * 64 + (size_t)gw * 8;
  for (int half = 0; half < 2; ++half) {
    if (wm == half) {
#pragma unroll
      for (int mi = 0; mi < 4; ++mi)
#pragma unroll
        for (int ni = 0; ni < 4; ++ni)
#pragma unroll
          for (int r = 0; r < 4; ++r)
            sm.ot[(mi << 4) + ((lane >> 4) << 2) + r][(wn << 6) + (ni << 4) + (lane & 15)] = acc[mi][ni][r];
    }
    __syncthreads();
    int tok = tokbase + half * 64 + lane;
    int td = tok >> 6, th = (tok >> 3) & 7, tw = tok & 7;
    size_t pos = posw + (size_t)td * 4096 + (size_t)th * 64 + tw;
    for (int cc = 0; cc < 32; ++cc) {
      int c = (cc << 2) + wid;
      float v = sm.ot[lane][c] + bo[nbase + c];
      out[(size_t)(nbase + c) * 65536 + pos] = v;
    }
    __syncthreads();
  }
}

// ---------------- launch ----------------
extern "C" void kernel_launch(void* const* d_in, const int* in_sizes, int n_in,
                              void* d_out, int out_size, void* d_ws, size_t ws_size,
                              hipStream_t stream) {
  const float* x     = (const float*)d_in[0];
  const float* gamma = (const float*)d_in[1];
  const float* beta  = (const float*)d_in[2];
  const float* wqkv  = (const float*)d_in[3];
  const float* wout  = (const float*)d_in[4];
  const float* bout  = (const float*)d_in[5];
  const float* btab  = (const float*)d_in[6];
  const int*   ridx  = (const int*)d_in[7];
  float* out = (float*)d_out;
  char* ws = (char*)d_ws;
  unsigned short* xn   = (unsigned short*)(ws);                  // 33,554,432 B
  unsigned short* qkv  = (unsigned short*)(ws + 33554432);       // 100,663,296 B (head-major)
  unsigned short* wqh  = (unsigned short*)(ws + 134217728);
  unsigned short* wql  = (unsigned short*)(ws + 134610944);
  unsigned short* woh  = (unsigned short*)(ws + 135004160);
  unsigned short* wol  = (unsigned short*)(ws + 135135232);
  float* bias2         = (float*)(ws + 135266304);
  unsigned short* attnout = xn;  // xn dead after k_qkv

  k_prepw<<<dim3(768), dim3(256), 0, stream>>>(wqkv, wout, wqh, wql, woh, wol);
  k_prepbias<<<dim3(2048), dim3(256), 0, stream>>>(btab, ridx, bias2);
  k_ln<<<dim3(1024), dim3(256), 0, stream>>>(x, gamma, beta, xn);
  k_qkv<<<dim3(512, 6), dim3(256), 0, stream>>>(xn, wqh, qkv);
  k_attn<<<dim3(256, 8), dim3(256), 0, stream>>>(qkv, bias2, attnout);
  k_outproj<<<dim3(512, 2), dim3(256), 0, stream>>>(attnout, woh, wol, bout, out);
}

// Round 16
// 181.570 us; speedup vs baseline: 1.1527x; 1.1432x over previous
//
#include <hip/hip_runtime.h>
#include <hip/hip_bf16.h>

// ---------------- types & helpers ----------------
typedef __attribute__((ext_vector_type(8))) short short8;
typedef __attribute__((ext_vector_type(4))) short s16x4;
typedef __attribute__((ext_vector_type(4))) float f32x4;
typedef __attribute__((ext_vector_type(2))) unsigned int u32x2;

#define NWIN 256      // number of windows
#define NW   256      // tokens per window
#define CH   256      // channels
#define NH   8
#define DH   32
#define ATTN_SCALE 0.17677669529663687f
#define LOG2E 1.4426950408889634f
#define QSCALE (ATTN_SCALE * LOG2E)   // folded into Q weights at prep

__device__ __forceinline__ unsigned short f2bf(float f) {
  union { float f; unsigned u; } v; v.f = f;
  unsigned r = v.u + 0x7FFFu + ((v.u >> 16) & 1u);   // round-to-nearest-even
  return (unsigned short)(r >> 16);
}
__device__ __forceinline__ float bf2f(unsigned short h) {
  union { unsigned u; float f; } v; v.u = ((unsigned)h) << 16;
  return v.f;
}
// XOR swizzle: 128-byte rows (8 x 16B slots) -- T2 pattern
__device__ __forceinline__ int swz128(int row, int kb) { return row * 128 + (kb ^ ((row & 7) << 4)); }
// async global->LDS, 16B per lane (dest must be linear: base + lane*16)
__device__ __forceinline__ void gload16(const unsigned short* g, unsigned short* l) {
  __builtin_amdgcn_global_load_lds((const __attribute__((address_space(1))) unsigned int*)(g),
                                   (__attribute__((address_space(3))) unsigned int*)(l), 16, 0, 0);
}

// ---------------- merged prep: weights (Q pre-scaled, wout hi/lo) + bias table ----------------
__global__ __launch_bounds__(256) void k_prep(const float* __restrict__ wqkv,
                                              const float* __restrict__ wout,
                                              const float* __restrict__ table,
                                              const int* __restrict__ relidx,
                                              unsigned short* __restrict__ wqh,
                                              unsigned short* __restrict__ woh,
                                              unsigned short* __restrict__ wol,
                                              float* __restrict__ bias2) {
  int idx = blockIdx.x * 256 + threadIdx.x;       // 0..524287
  int h = idx >> 16;
  int qk = idx & 65535;
  bias2[idx] = table[relidx[qk] * 8 + h] * LOG2E;
  if (idx < 196608) {
    int k = idx / 768, n = idx % 768;
    float v = wqkv[idx];
    if (n < 256) v *= QSCALE;                     // fold scale*log2e into Q
    wqh[n * 256 + k] = f2bf(v);                   // single-bf16 (r13 numerics)
  }
  if (idx < 65536) {
    int k = idx >> 8, n = idx & 255;
    float v = wout[idx];
    unsigned short hi = f2bf(v);
    woh[n * 256 + k] = hi;
    wol[n * 256 + k] = f2bf(v - bf2f(hi));
  }
}

// ---------------- LN + window gather (float4 loads) ----------------
__global__ __launch_bounds__(256) void k_ln(const float* __restrict__ x,
                                            const float* __restrict__ gamma,
                                            const float* __restrict__ beta,
                                            unsigned short* __restrict__ xn) {
  __shared__ unsigned short buf[256][66];
  __shared__ float stats[2][16][64];
  int bid = blockIdx.x;
  int d = bid >> 6, h = bid & 63;
  int t = threadIdx.x;
  int wq = (t & 15) << 2;      // w base: 0..60 step 4
  int cp = t >> 4;             // 0..15
  const float* xrow = x + (size_t)d * 4096 + (size_t)h * 64;
  float s0[4] = {0.f, 0.f, 0.f, 0.f}, s1[4] = {0.f, 0.f, 0.f, 0.f};
  for (int ci = 0; ci < 16; ++ci) {
    int c = ci * 16 + cp;
    f32x4 v = *(const f32x4*)(xrow + (size_t)c * 65536 + wq);
    unsigned pk01 = (unsigned)f2bf(v[0]) | ((unsigned)f2bf(v[1]) << 16);
    unsigned pk23 = (unsigned)f2bf(v[2]) | ((unsigned)f2bf(v[3]) << 16);
    *(unsigned*)&buf[c][wq]     = pk01;
    *(unsigned*)&buf[c][wq + 2] = pk23;
#pragma unroll
    for (int j = 0; j < 4; ++j) { s0[j] += v[j]; s1[j] += v[j] * v[j]; }
  }
#pragma unroll
  for (int j = 0; j < 4; ++j) { stats[0][cp][wq + j] = s0[j]; stats[1][cp][wq + j] = s1[j]; }
  __syncthreads();
  int lane = t & 63, wv = t >> 6;
  int winb = (d >> 2) * 64 + (h >> 3) * 8;
  int tokb = (d & 3) * 64 + (h & 7) * 8;
  for (int wi = 0; wi < 16; ++wi) {
    int w2 = wi * 4 + wv;
    float sum = 0.f, sq = 0.f;
#pragma unroll
    for (int i = 0; i < 16; ++i) { sum += stats[0][i][w2]; sq += stats[1][i][w2]; }
    float mu = sum * 0.00390625f;
    float var = sq * 0.00390625f - mu * mu;
    float rstd = rsqrtf(var + 1e-5f);
    int win = winb + (w2 >> 3);
    int tok = tokb + (w2 & 7);
    unsigned short* dst = xn + ((size_t)win * NW + tok) * CH;
    for (int cc = 0; cc < 4; ++cc) {
      int c = cc * 64 + lane;
      float v = bf2f(buf[c][w2]);
      dst[c] = f2bf((v - mu) * rstd * gamma[c] + beta[c]);
    }
  }
}

// ---------------- QKV GEMM (1D grid + chunked XCD swizzle: A-tile L2-reuse) ----------------
// gid -> xcd = gid&7 owns mtiles [xcd*64, xcd*64+64); consecutive slots iterate
// ntile fastest so the 6 blocks sharing an A-tile run back-to-back on one XCD.
__global__ __launch_bounds__(256) void k_qkv(const unsigned short* __restrict__ xn,
                                             const unsigned short* __restrict__ bhi,
                                             unsigned short* __restrict__ qkvH) {
  __shared__ unsigned short sA[8192], sBh[8192];
  int t = threadIdx.x;
  int gid = blockIdx.x;                    // 0..3071
  int xcd = gid & 7, s = gid >> 3;         // s: 0..383
  int mbase = ((xcd << 6) + s / 6) << 7;
  int nbase = (s % 6) << 7;
  int wid = t >> 6, lane = t & 63;
  int wm = wid >> 1, wn = wid & 1;
  f32x4 acc[4][4];
#pragma unroll
  for (int i = 0; i < 4; ++i)
#pragma unroll
    for (int j = 0; j < 4; ++j) acc[i][j] = (f32x4)(0.f);
  for (int kt = 0; kt < 4; ++kt) {
#pragma unroll
    for (int i = 0; i < 4; ++i) {
      int ch = t + (i << 8);
      int row = ch >> 3, sl = ch & 7;
      int gs = sl ^ (row & 7);             // pre-swizzled source slot
      size_t go = (size_t)(mbase + row) * 256 + (kt << 6) + (gs << 3);
      size_t gb = (size_t)(nbase + row) * 256 + (kt << 6) + (gs << 3);
      gload16(xn + go,  sA  + ch * 8);     // linear LDS dest: byte ch*16
      gload16(bhi + gb, sBh + ch * 8);
    }
    __syncthreads();
#pragma unroll
    for (int kk = 0; kk < 2; ++kk) {
      int kb = (kk << 6) + ((lane >> 4) << 4);
      short8 a[4], bh[4];
#pragma unroll
      for (int mi = 0; mi < 4; ++mi) {
        int row = (wm << 6) + (mi << 4) + (lane & 15);
        a[mi] = *(const short8*)((char*)sA + swz128(row, kb));
      }
#pragma unroll
      for (int ni = 0; ni < 4; ++ni) {
        int row = (wn << 6) + (ni << 4) + (lane & 15);
        bh[ni] = *(const short8*)((char*)sBh + swz128(row, kb));
      }
#pragma unroll
      for (int mi = 0; mi < 4; ++mi)
#pragma unroll
        for (int ni = 0; ni < 4; ++ni)
          acc[mi][ni] = __builtin_amdgcn_mfma_f32_16x16x32_bf16(a[mi], bh[ni], acc[mi][ni], 0, 0, 0);
    }
    __syncthreads();
  }
#pragma unroll
  for (int mi = 0; mi < 4; ++mi)
#pragma unroll
    for (int ni = 0; ni < 4; ++ni)
#pragma unroll
      for (int r = 0; r < 4; ++r) {
        int m = mbase + (wm << 6) + (mi << 4) + ((lane >> 4) << 2) + r;
        int n = nbase + (wn << 6) + (ni << 4) + (lane & 15);
        int mat = n >> 8, hd = (n >> 5) & 7, dh = n & 31;
        qkvH[((size_t)(mat * 8 + hd) * 65536 + m) * 32 + dh] = f2bf(acc[mi][ni][r]);
      }
}

// ---------------- attention v15 (unchanged): prefetched bias as MFMA C-operand ----------------
__global__ __launch_bounds__(256) void k_attn(const unsigned short* __restrict__ qkvH,
                                              const float* __restrict__ bias2,
                                              unsigned short* __restrict__ attnout) {
  __shared__ unsigned short Vt[8192];    // [32 dh][256 tok] 512B rows, XOR swizzled (16KB)
  __shared__ unsigned short Kt[8192];    // [256 tok][32 dh] 64B rows, XOR swizzled (16KB)
  int win = blockIdx.x, head = blockIdx.y;
  int t = threadIdx.x, wid = t >> 6, lane = t & 63;
  int l15 = lane & 15, g = lane >> 4;
  const unsigned short* Qg = qkvH + ((size_t)(head)      * 65536 + win * 256) * 32;
  const unsigned short* Kg = qkvH + ((size_t)(8 + head)  * 65536 + win * 256) * 32;
  const unsigned short* Vg = qkvH + ((size_t)(16 + head) * 65536 + win * 256) * 32;

  { // stage V transposed: thread t handles V row tok=t (contiguous 64B rows -> coalesced)
    const unsigned short* vrow = Vg + (size_t)t * 32;
    short8 v0 = *(const short8*)(vrow);
    short8 v1 = *(const short8*)(vrow + 8);
    short8 v2 = *(const short8*)(vrow + 16);
    short8 v3 = *(const short8*)(vrow + 24);
    int tb = t * 2;
#pragma unroll
    for (int j = 0; j < 8; ++j) {
      int sj = tb ^ (j << 4);
      *(unsigned short*)((char*)Vt + (j)      * 512 + sj)       = (unsigned short)v0[j];
      *(unsigned short*)((char*)Vt + (8 + j)  * 512 + (sj ^ 8)) = (unsigned short)v1[j];
      *(unsigned short*)((char*)Vt + (16 + j) * 512 + sj)       = (unsigned short)v2[j];
      *(unsigned short*)((char*)Vt + (24 + j) * 512 + (sj ^ 8)) = (unsigned short)v3[j];
    }
  }
  { // stage K packed: thread t -> row t (contiguous source), chunk-XOR swizzle
    const unsigned short* krow = Kg + (size_t)t * 32;
    short8 k0 = *(const short8*)(krow);
    short8 k1 = *(const short8*)(krow + 8);
    short8 k2 = *(const short8*)(krow + 16);
    short8 k3 = *(const short8*)(krow + 24);
    char* kd = (char*)Kt + t * 64;
    int ks = ((t >> 1) & 3) << 4;
    *(short8*)(kd + (0  ^ ks)) = k0;
    *(short8*)(kd + (16 ^ ks)) = k1;
    *(short8*)(kd + (32 ^ ks)) = k2;
    *(short8*)(kd + (48 ^ ks)) = k3;
  }
  short8 bq[4];
#pragma unroll
  for (int qt = 0; qt < 4; ++qt)
    bq[qt] = *(const short8*)(Qg + (size_t)(wid * 64 + qt * 16 + l15) * 32 + g * 8);

  f32x4 o[4][2];
#pragma unroll
  for (int qt = 0; qt < 4; ++qt) { o[qt][0] = (f32x4)(0.f); o[qt][1] = (f32x4)(0.f); }
  float l_[4] = {0.f, 0.f, 0.f, 0.f};
  const float* bthread = bias2 + ((size_t)head << 16) + (size_t)(wid * 64 + l15) * 256 + g * 4;
  int vswz = ((l15 & 7) << 4) ^ (l15 & 8);   // V read swizzle
  int kswz = ((l15 >> 1) & 3) << 4;          // K read swizzle (lane-constant)

  // prefetch bias for (ck=0, qt=0)
  f32x4 nb0, nb1, nb2, nb3;
  {
    const float* bp = bthread;
    nb0 = *(const f32x4*)(bp);
    nb1 = *(const f32x4*)(bp + 16);
    nb2 = *(const f32x4*)(bp + 32);
    nb3 = *(const f32x4*)(bp + 48);
  }

  __syncthreads();

  for (int ck = 0; ck < 4; ++ck) {
    short8 ak[4];
#pragma unroll
    for (int tt = 0; tt < 4; ++tt)
      ak[tt] = *(const short8*)((char*)Kt + (ck * 64 + tt * 16 + l15) * 64 + ((g * 16) ^ kswz));
#pragma unroll
    for (int qt = 0; qt < 4; ++qt) {
      // consume current (prefetched) bias as MFMA C-operand; issue next prefetch now
      f32x4 cb[4];
      cb[0] = nb0; cb[1] = nb1; cb[2] = nb2; cb[3] = nb3;
      if (!(ck == 3 && qt == 3)) {
        int nqt = (qt + 1) & 3;
        int nck = (qt == 3) ? ck + 1 : ck;
        const float* bp = bthread + (size_t)nqt * 4096 + nck * 64;  // floats
        nb0 = *(const f32x4*)(bp);
        nb1 = *(const f32x4*)(bp + 16);
        nb2 = *(const f32x4*)(bp + 32);
        nb3 = *(const f32x4*)(bp + 48);
      }
      f32x4 z[4];
      __builtin_amdgcn_s_setprio(1);
#pragma unroll
      for (int tt = 0; tt < 4; ++tt)
        z[tt] = __builtin_amdgcn_mfma_f32_16x16x32_bf16(ak[tt], bq[qt], cb[tt], 0, 0, 0);
      __builtin_amdgcn_s_setprio(0);
      u32x2 wPq[4];
#pragma unroll
      for (int tt = 0; tt < 4; ++tt) {
        float p0 = __builtin_amdgcn_exp2f(z[tt][0]);
        float p1 = __builtin_amdgcn_exp2f(z[tt][1]);
        float p2 = __builtin_amdgcn_exp2f(z[tt][2]);
        float p3 = __builtin_amdgcn_exp2f(z[tt][3]);
        l_[qt] += (p0 + p1) + (p2 + p3);
        __hip_bfloat162 lo = __float22bfloat162_rn(float2{p0, p1});
        __hip_bfloat162 hi = __float22bfloat162_rn(float2{p2, p3});
        u32x2 pk;
        pk.x = *(unsigned int*)&lo;
        pk.y = *(unsigned int*)&hi;
        wPq[tt] = pk;
      }
      // PV for this qt (K=16 per tt), P straight from registers
      __builtin_amdgcn_s_setprio(1);
#pragma unroll
      for (int tt = 0; tt < 4; ++tt) {
        int tokb = (ck * 128 + tt * 32 + g * 8) ^ vswz;
        s16x4 pa = __builtin_bit_cast(s16x4, wPq[tt]);
#pragma unroll
        for (int dht = 0; dht < 2; ++dht) {
          s16x4 vb = *(const s16x4*)((char*)Vt + (dht * 16 + l15) * 512 + tokb);
          o[qt][dht] = __builtin_amdgcn_mfma_f32_16x16x16bf16_1k(pa, vb, o[qt][dht], 0, 0, 0);
        }
      }
      __builtin_amdgcn_s_setprio(0);
    }
  }
#pragma unroll
  for (int qt = 0; qt < 4; ++qt) {
    float lq = l_[qt];
    lq += __shfl_xor(lq, 16);
    lq += __shfl_xor(lq, 32);
    float linv = 1.0f / lq;
#pragma unroll
    for (int r = 0; r < 4; ++r) {
      float lr = __shfl(linv, g * 4 + r);
      int q = wid * 64 + qt * 16 + g * 4 + r;
      unsigned short* dst = attnout + ((size_t)(win * NW + q)) * CH + head * DH + l15;
      dst[0]  = f2bf(o[qt][0][r] * lr);
      dst[16] = f2bf(o[qt][1][r] * lr);
    }
  }
}

// ---------------- out-proj GEMM + bias + window-merge scatter (1D grid + XCD swizzle) ----------------
union SmemOP {
  struct { unsigned short A[8192], Bh[8192], Bl[8192]; } st;
  float ot[64][129];
};
__global__ __launch_bounds__(256) void k_outproj(const unsigned short* __restrict__ attnout,
                                                 const unsigned short* __restrict__ bhi,
                                                 const unsigned short* __restrict__ blo,
                                                 const float* __restrict__ bo,
                                                 float* __restrict__ out) {
  __shared__ SmemOP sm;
  int t = threadIdx.x;
  int gid = blockIdx.x;                    // 0..1023
  int xcd = gid & 7, s = gid >> 3;         // s: 0..127
  int mbase = ((xcd << 6) + (s >> 1)) << 7;
  int nbase = (s & 1) << 7;
  int wid = t >> 6, lane = t & 63;
  int wm = wid >> 1, wn = wid & 1;
  f32x4 acc[4][4];
#pragma unroll
  for (int i = 0; i < 4; ++i)
#pragma unroll
    for (int j = 0; j < 4; ++j) acc[i][j] = (f32x4)(0.f);
  for (int kt = 0; kt < 4; ++kt) {
#pragma unroll
    for (int i = 0; i < 4; ++i) {
      int ch = t + (i << 8);
      int row = ch >> 3, c16 = ch & 7;
      size_t go = (size_t)(mbase + row) * 256 + (kt << 6) + (c16 << 3);
      short8 va = *(const short8*)(attnout + go);
      *(short8*)((char*)sm.st.A + swz128(row, c16 << 4)) = va;
      size_t gb = (size_t)(nbase + row) * 256 + (kt << 6) + (c16 << 3);
      short8 vh = *(const short8*)(bhi + gb);
      *(short8*)((char*)sm.st.Bh + swz128(row, c16 << 4)) = vh;
      short8 vl = *(const short8*)(blo + gb);
      *(short8*)((char*)sm.st.Bl + swz128(row, c16 << 4)) = vl;
    }
    __syncthreads();
#pragma unroll
    for (int kk = 0; kk < 2; ++kk) {
      int kb = (kk << 6) + ((lane >> 4) << 4);
      short8 a[4], bh[4], bl[4];
#pragma unroll
      for (int mi = 0; mi < 4; ++mi) {
        int row = (wm << 6) + (mi << 4) + (lane & 15);
        a[mi] = *(const short8*)((char*)sm.st.A + swz128(row, kb));
      }
#pragma unroll
      for (int ni = 0; ni < 4; ++ni) {
        int row = (wn << 6) + (ni << 4) + (lane & 15);
        bh[ni] = *(const short8*)((char*)sm.st.Bh + swz128(row, kb));
        bl[ni] = *(const short8*)((char*)sm.st.Bl + swz128(row, kb));
      }
#pragma unroll
      for (int mi = 0; mi < 4; ++mi)
#pragma unroll
        for (int ni = 0; ni < 4; ++ni) {
          acc[mi][ni] = __builtin_amdgcn_mfma_f32_16x16x32_bf16(a[mi], bh[ni], acc[mi][ni], 0, 0, 0);
          acc[mi][ni] = __builtin_amdgcn_mfma_f32_16x16x32_bf16(a[mi], bl[ni], acc[mi][ni], 0, 0, 0);
        }
    }
    __syncthreads();
  }
  int win = mbase >> 8;
  int tokbase = mbase & 255;
  int gd = win >> 6, gh = (win >> 3) & 7, gw = win & 7;
  size_t posw = (size_t)gd * 4 * 4096 + (size_t)gh * 8 * 64 + (size_t)gw * 8;
  for (int half = 0; half < 2; ++half) {
    if (wm == half) {
#pragma unroll
      for (int mi = 0; mi < 4; ++mi)
#pragma unroll
        for (int ni = 0; ni < 4; ++ni)
#pragma unroll
          for (int r = 0; r < 4; ++r)
            sm.ot[(mi << 4) + ((lane >> 4) << 2) + r][(wn << 6) + (ni << 4) + (lane & 15)] = acc[mi][ni][r];
    }
    __syncthreads();
    int tok = tokbase + half * 64 + lane;
    int td = tok >> 6, th = (tok >> 3) & 7, tw = tok & 7;
    size_t pos = posw + (size_t)td * 4096 + (size_t)th * 64 + tw;
    for (int cc = 0; cc < 32; ++cc) {
      int c = (cc << 2) + wid;
      float v = sm.ot[lane][c] + bo[nbase + c];
      out[(size_t)(nbase + c) * 65536 + pos] = v;
    }
    __syncthreads();
  }
}

// ---------------- launch ----------------
extern "C" void kernel_launch(void* const* d_in, const int* in_sizes, int n_in,
                              void* d_out, int out_size, void* d_ws, size_t ws_size,
                              hipStream_t stream) {
  const float* x     = (const float*)d_in[0];
  const float* gamma = (const float*)d_in[1];
  const float* beta  = (const float*)d_in[2];
  const float* wqkv  = (const float*)d_in[3];
  const float* wout  = (const float*)d_in[4];
  const float* bout  = (const float*)d_in[5];
  const float* btab  = (const float*)d_in[6];
  const int*   ridx  = (const int*)d_in[7];
  float* out = (float*)d_out;
  char* ws = (char*)d_ws;
  unsigned short* xn   = (unsigned short*)(ws);                  // 33,554,432 B
  unsigned short* qkv  = (unsigned short*)(ws + 33554432);       // 100,663,296 B (head-major)
  unsigned short* wqh  = (unsigned short*)(ws + 134217728);      // 393,216 B
  unsigned short* woh  = (unsigned short*)(ws + 135004160);      // 131,072 B
  unsigned short* wol  = (unsigned short*)(ws + 135135232);      // 131,072 B
  float* bias2         = (float*)(ws + 135266304);               // 2,097,152 B
  unsigned short* attnout = xn;  // xn dead after k_qkv

  k_prep<<<dim3(2048), dim3(256), 0, stream>>>(wqkv, wout, btab, ridx, wqh, woh, wol, bias2);
  k_ln<<<dim3(1024), dim3(256), 0, stream>>>(x, gamma, beta, xn);
  k_qkv<<<dim3(3072), dim3(256), 0, stream>>>(xn, wqh, qkv);
  k_attn<<<dim3(256, 8), dim3(256), 0, stream>>>(qkv, bias2, attnout);
  k_outproj<<<dim3(1024), dim3(256), 0, stream>>>(attnout, woh, wol, bout, out);
}